// Round 5
// baseline (92.718 us; speedup 1.0000x reference)
//
#include <hip/hip_runtime.h>
#include <hip/hip_bf16.h>
#include <stdint.h>

#define THRESH_FACTOR 0.05f

typedef __attribute__((ext_vector_type(8))) short short8;
typedef __attribute__((ext_vector_type(16))) float f32x16;

__device__ inline uint32_t cvtpk_bf16(float lo, float hi) {
    uint32_t r;
    asm volatile("v_cvt_pk_bf16_f32 %0, %1, %2" : "=v"(r) : "v"(lo), "v"(hi));
    return r;
}

// ---------------- Kernel 1: per-row ternary quantization (linear out) ------
__global__ void __launch_bounds__(256) quant_tern(
        const float* __restrict__ W, unsigned short* __restrict__ Wq,
        float* __restrict__ scale, int IN)
{
    const int row = blockIdx.x;
    const int tid = threadIdx.x;
    const int lane = tid & 63;
    const int wid = tid >> 6;
    const float4* wr4 = (const float4*)(W + (size_t)row * IN);
    const int n4 = IN >> 2;

    float s = 0.f;
    for (int i = tid; i < n4; i += 256) {
        float4 v = wr4[i];
        s += fabsf(v.x) + fabsf(v.y) + fabsf(v.z) + fabsf(v.w);
    }
    #pragma unroll
    for (int off = 32; off; off >>= 1) s += __shfl_down(s, off);
    __shared__ float redA[4], redB[4];
    if (lane == 0) redA[wid] = s;
    __syncthreads();
    const float delta = THRESH_FACTOR * (redA[0] + redA[1] + redA[2] + redA[3]) / (float)IN;
    __syncthreads();

    float ks = 0.f, kn = 0.f;
    ushort4* out4 = (ushort4*)(Wq + (size_t)row * IN);
    for (int i = tid; i < n4; i += 256) {
        float4 v = wr4[i];
        ushort4 t;
        float a; unsigned int u;
        a = fabsf(v.x); u = __float_as_uint(v.x);
        if (a > delta) { ks += a; kn += 1.f; t.x = (unsigned short)(0x3F80u | ((u >> 16) & 0x8000u)); } else t.x = 0;
        a = fabsf(v.y); u = __float_as_uint(v.y);
        if (a > delta) { ks += a; kn += 1.f; t.y = (unsigned short)(0x3F80u | ((u >> 16) & 0x8000u)); } else t.y = 0;
        a = fabsf(v.z); u = __float_as_uint(v.z);
        if (a > delta) { ks += a; kn += 1.f; t.z = (unsigned short)(0x3F80u | ((u >> 16) & 0x8000u)); } else t.z = 0;
        a = fabsf(v.w); u = __float_as_uint(v.w);
        if (a > delta) { ks += a; kn += 1.f; t.w = (unsigned short)(0x3F80u | ((u >> 16) & 0x8000u)); } else t.w = 0;
        out4[i] = t;
    }
    #pragma unroll
    for (int off = 32; off; off >>= 1) { ks += __shfl_down(ks, off); kn += __shfl_down(kn, off); }
    if (lane == 0) { redA[wid] = ks; redB[wid] = kn; }
    __syncthreads();
    if (tid == 0) {
        float tks = redA[0] + redA[1] + redA[2] + redA[3];
        float tkn = redB[0] + redB[1] + redB[2] + redB[3];
        scale[row] = tks / fmaxf(tkn, 1.f);
    }
}

// ---------------- Kernel 2: fused-cast MFMA GEMM ---------------------------
// C = (f32->bf16(X)) @ Wq^T * scale + bias.  BM=BN=128, BK=128.
// 8 waves = 2 wc (N) x 4 kg (K-split). Wave tile 128(M)x64(N): 4m x 2n frags
// of 32x32x16. All-reg staging (T14): loads(t+1) at step top (compiler-derived
// vmcnt via reg deps), cvt+ds_write after MFMA, ONE lgkm0+barrier per step.
// LDS swizzle: chunk pos stored at pos^(row&15) (16-slot full permutation ->
// conflict-free quarters). kg merge via LDS (aliased), 2 rounds.
#define BM 128
#define BN 128
#define BK 128
#define THREADS 512

__global__ void __launch_bounds__(512, 2) gemm_tern(
        const float* __restrict__ X,             // [M][K] f32
        const unsigned short* __restrict__ Wq,   // [N][K] bf16 bits (linear)
        const float* __restrict__ scale,         // [N]
        const float* __restrict__ bias,          // [N]
        float* __restrict__ C,                   // [M][N] f32
        int M, int N, int K)
{
    __shared__ __attribute__((aligned(16))) union SMem {
        struct { unsigned short A[2][BM * BK]; unsigned short B[2][BN * BK]; } s; // 128 KB
        float merge[4][8192];                                                     // 128 KB
    } u;

    const int tid    = threadIdx.x;
    const int lane   = tid & 63;
    const int lane31 = lane & 31;
    const int khalf  = lane >> 5;
    const int wid    = tid >> 6;   // 0..7
    const int wc     = wid & 1;    // N-half 0/1
    const int kg     = wid >> 1;   // K-group 0..3

    // XCD-aware bijective swizzle (nwg=256, divisible by 8)
    const int nwg = gridDim.x;
    const int bid = blockIdx.x;
    const int swz = (bid & 7) * (nwg >> 3) + (bid >> 3);
    const int ntn = N / BN;
    const int bm0 = (swz / ntn) * BM;
    const int bn0 = (swz % ntn) * BN;

    f32x16 acc[4][2];
    #pragma unroll
    for (int m = 0; m < 4; ++m)
        #pragma unroll
        for (int n = 0; n < 2; ++n)
            #pragma unroll
            for (int r = 0; r < 16; ++r)
                acc[m][n][r] = 0.f;

    // staging assignment: tile = 128 rows x 16 chunks(16B); 4 chunks/thread
    const float4* aptr[4];
    const uint4*  bptr[4];
    int a_lds[4], b_lds[4];
    #pragma unroll
    for (int c = 0; c < 4; ++c) {
        int slot = c * THREADS + tid;
        int row = slot >> 4, pos = slot & 15;
        aptr[c] = (const float4*)(X + (size_t)(bm0 + row) * K + pos * 8);
        a_lds[c] = row * BK + ((pos ^ (row & 15)) * 8);
        bptr[c] = (const uint4*)(Wq + (size_t)(bn0 + row) * K + pos * 8);
        b_lds[c] = row * BK + ((pos ^ (row & 15)) * 8);
    }

    const int NT = K / BK;   // 32

    // ---- prologue: stage tile 0 ----
    {
        float4 pa[8]; uint4 pb[4];
        #pragma unroll
        for (int c = 0; c < 4; ++c) {
            pa[2 * c]     = aptr[c][0];
            pa[2 * c + 1] = aptr[c][1];
            pb[c]         = *bptr[c];
            aptr[c] += 32;   // advance 128 f32 (32 float4)
            bptr[c] += 16;   // advance 128 bf16 (16 uint4)  [R4 bug was +=8]
        }
        #pragma unroll
        for (int c = 0; c < 4; ++c) {
            uint4 o;
            o.x = cvtpk_bf16(pa[2 * c].x,     pa[2 * c].y);
            o.y = cvtpk_bf16(pa[2 * c].z,     pa[2 * c].w);
            o.z = cvtpk_bf16(pa[2 * c + 1].x, pa[2 * c + 1].y);
            o.w = cvtpk_bf16(pa[2 * c + 1].z, pa[2 * c + 1].w);
            *(uint4*)&u.s.A[0][a_lds[c]] = o;
            *(uint4*)&u.s.B[0][b_lds[c]] = pb[c];
        }
        asm volatile("s_waitcnt lgkmcnt(0)" ::: "memory");
        __builtin_amdgcn_s_barrier();
    }

    for (int t = 0; t < NT; ++t) {
        const int nxt = t + 1;
        float4 la[8]; uint4 lb[4];
        if (nxt < NT) {
            #pragma unroll
            for (int c = 0; c < 4; ++c) {
                la[2 * c]     = aptr[c][0];
                la[2 * c + 1] = aptr[c][1];
                lb[c]         = *bptr[c];
                aptr[c] += 32;
                bptr[c] += 16;   // [R4 bug was +=8]
            }
        }
        __builtin_amdgcn_sched_barrier(0);   // pin load issue at step top

        const unsigned short* Abuf = u.s.A[t & 1];
        const unsigned short* Bbuf = u.s.B[t & 1];
        #pragma unroll
        for (int kk = 0; kk < 2; ++kk) {
            const int cbase = kg * 4 + kk * 2 + khalf;   // logical chunk 0..15
            short8 af[4], bf[2];
            #pragma unroll
            for (int m = 0; m < 4; ++m) {
                int r = m * 32 + lane31;
                af[m] = *(const short8*)&Abuf[r * BK + ((cbase ^ (r & 15)) * 8)];
            }
            #pragma unroll
            for (int n = 0; n < 2; ++n) {
                int r = wc * 64 + n * 32 + lane31;
                bf[n] = *(const short8*)&Bbuf[r * BK + ((cbase ^ (r & 15)) * 8)];
            }
            __builtin_amdgcn_s_setprio(1);
            #pragma unroll
            for (int m = 0; m < 4; ++m)
                #pragma unroll
                for (int n = 0; n < 2; ++n)
                    acc[m][n] = __builtin_amdgcn_mfma_f32_32x32x16_bf16(
                        af[m], bf[n], acc[m][n], 0, 0, 0);
            __builtin_amdgcn_s_setprio(0);
        }

        if (nxt < NT) {
            unsigned short* An = (unsigned short*)u.s.A[nxt & 1];
            unsigned short* Bn = (unsigned short*)u.s.B[nxt & 1];
            #pragma unroll
            for (int c = 0; c < 4; ++c) {
                uint4 o;
                o.x = cvtpk_bf16(la[2 * c].x,     la[2 * c].y);
                o.y = cvtpk_bf16(la[2 * c].z,     la[2 * c].w);
                o.z = cvtpk_bf16(la[2 * c + 1].x, la[2 * c + 1].y);
                o.w = cvtpk_bf16(la[2 * c + 1].z, la[2 * c + 1].w);
                *(uint4*)&An[a_lds[c]] = o;
                *(uint4*)&Bn[b_lds[c]] = lb[c];
            }
        }
        asm volatile("s_waitcnt lgkmcnt(0)" ::: "memory");
        __builtin_amdgcn_s_barrier();        // tile t+1 in LDS; all reads of t done
    }

    // ---- kg merge through LDS (aliases staging; loop fully barriered) ----
    // region j = ((float*)&u) + j*8192; lane-major, 16B slots XOR-swizzled.
    #define WRITE_ACC(j)                                                        \
        do {                                                                    \
            float* rg = (float*)&u + (j) * 8192 + lane * 128;                   \
            _Pragma("unroll")                                                   \
            for (int m = 0; m < 4; ++m)                                         \
                _Pragma("unroll")                                               \
                for (int n = 0; n < 2; ++n)                                     \
                    _Pragma("unroll")                                           \
                    for (int q4 = 0; q4 < 4; ++q4) {                            \
                        int q = (m * 2 + n) * 4 + q4;                           \
                        float4 v = make_float4(acc[m][n][q4 * 4 + 0],           \
                                               acc[m][n][q4 * 4 + 1],           \
                                               acc[m][n][q4 * 4 + 2],           \
                                               acc[m][n][q4 * 4 + 3]);          \
                        *(float4*)&rg[(q ^ (lane & 15)) * 4] = v;               \
                    }                                                           \
        } while (0)
    #define ADD_ACC(j)                                                          \
        do {                                                                    \
            const float* rg = (const float*)&u + (j) * 8192 + lane * 128;       \
            _Pragma("unroll")                                                   \
            for (int m = 0; m < 4; ++m)                                         \
                _Pragma("unroll")                                               \
                for (int n = 0; n < 2; ++n)                                     \
                    _Pragma("unroll")                                           \
                    for (int q4 = 0; q4 < 4; ++q4) {                            \
                        int q = (m * 2 + n) * 4 + q4;                           \
                        float4 v = *(const float4*)&rg[(q ^ (lane & 15)) * 4];  \
                        acc[m][n][q4 * 4 + 0] += v.x;                           \
                        acc[m][n][q4 * 4 + 1] += v.y;                           \
                        acc[m][n][q4 * 4 + 2] += v.z;                           \
                        acc[m][n][q4 * 4 + 3] += v.w;                           \
                    }                                                           \
        } while (0)

    if (kg == 1) WRITE_ACC(wc * 2 + 0);
    if (kg == 3) WRITE_ACC(wc * 2 + 1);
    __syncthreads();
    if (kg == 0) ADD_ACC(wc * 2 + 0);
    if (kg == 2) ADD_ACC(wc * 2 + 1);
    __syncthreads();
    if (kg == 2) WRITE_ACC(wc);
    __syncthreads();
    if (kg == 0) {
        ADD_ACC(wc);
        #pragma unroll
        for (int n = 0; n < 2; ++n) {
            int col = bn0 + wc * 64 + n * 32 + lane31;
            float sc = scale[col];
            float bs = bias[col];
            #pragma unroll
            for (int m = 0; m < 4; ++m) {
                int rbase = bm0 + m * 32 + 4 * khalf;
                #pragma unroll
                for (int r = 0; r < 16; ++r) {
                    int row = rbase + (r & 3) + 8 * (r >> 2);
                    C[(size_t)row * N + col] = acc[m][n][r] * sc + bs;
                }
            }
        }
    }
    #undef WRITE_ACC
    #undef ADD_ACC
}

extern "C" void kernel_launch(void* const* d_in, const int* in_sizes, int n_in,
                              void* d_out, int out_size, void* d_ws, size_t ws_size,
                              hipStream_t stream)
{
    const float* x    = (const float*)d_in[0];
    const float* w    = (const float*)d_in[1];
    const float* bias = (const float*)d_in[2];
    float* out = (float*)d_out;

    const int OUT = in_sizes[2];            // 1024
    const int IN  = in_sizes[1] / OUT;      // 4096
    const int B   = in_sizes[0] / IN;       // 4096

    // workspace: w_tern_bf16 [OUT*IN] | scale [OUT]
    unsigned short* Wq = (unsigned short*)d_ws;
    float* scale = (float*)(Wq + (size_t)OUT * IN);

    quant_tern<<<OUT, 256, 0, stream>>>(w, Wq, scale, IN);
    gemm_tern<<<dim3((B / BM) * (OUT / BN)), THREADS, 0, stream>>>(
        x, Wq, scale, bias, out, B, OUT, IN);
}

// Round 6
// 73.585 us; speedup vs baseline: 1.2600x; 1.2600x over previous
//
#include <hip/hip_runtime.h>
#include <hip/hip_bf16.h>
#include <stdint.h>

#define THRESH_FACTOR 0.05f

typedef __attribute__((ext_vector_type(8))) short short8;
typedef __attribute__((ext_vector_type(16))) float f32x16;

__device__ inline unsigned int bfbits(float f) {
    unsigned int u = __float_as_uint(f);
    return (u + 0x7FFFu + ((u >> 16) & 1u)) >> 16;   // RNE bf16 bits
}

// Bank-true chunk swizzle: rows 256B => bank_group = (chunk&7)*4 only.
// s(r) = (r&7) ^ ((r>>3)&7): 8 consecutive rows -> 8 distinct groups, and the
// 4-row collision set {r, r+8, r+16, r+24} -> 4 distinct groups.
__device__ inline int swz_row(int r) { return (r & 7) ^ ((r >> 3) & 7); }

// ---------------- Kernel 1: per-row ternary quantization -----------------
// One block (256 threads) per output row. Produces bf16 ternary weights
// (exact {-1,0,+1}) in CHUNK-SWIZZLED layout: within each 8-chunk half of a
// 16-chunk (128-elem) K-block, chunk c stored at position c ^ s(row).
__global__ void __launch_bounds__(256) quant_tern(
        const float* __restrict__ W, unsigned short* __restrict__ Wq,
        float* __restrict__ scale, int IN)
{
    const int row = blockIdx.x;
    const int tid = threadIdx.x;
    const int lane = tid & 63;
    const int wid = tid >> 6;
    const float4* wr4 = (const float4*)(W + (size_t)row * IN);
    const int n4 = IN >> 2;

    float s = 0.f;
    for (int i = tid; i < n4; i += 256) {
        float4 v = wr4[i];
        s += fabsf(v.x) + fabsf(v.y) + fabsf(v.z) + fabsf(v.w);
    }
    #pragma unroll
    for (int off = 32; off; off >>= 1) s += __shfl_down(s, off);
    __shared__ float redA[4], redB[4];
    if (lane == 0) redA[wid] = s;
    __syncthreads();
    const float delta = THRESH_FACTOR * (redA[0] + redA[1] + redA[2] + redA[3]) / (float)IN;
    __syncthreads();   // all delta-reads done before redA reuse

    const int sr = swz_row(row);
    float ks = 0.f, kn = 0.f;
    uint4* out16 = (uint4*)(Wq + (size_t)row * IN);   // 16B chunks
    const int n8 = IN >> 3;                            // chunks per row
    for (int i = tid; i < n8; i += 256) {
        float4 v0 = wr4[2 * i], v1 = wr4[2 * i + 1];
        float vs[8] = {v0.x, v0.y, v0.z, v0.w, v1.x, v1.y, v1.z, v1.w};
        unsigned int h[8];
        #pragma unroll
        for (int j = 0; j < 8; ++j) {
            float a = fabsf(vs[j]);
            unsigned int u = __float_as_uint(vs[j]);
            if (a > delta) { ks += a; kn += 1.f; h[j] = 0x3F80u | ((u >> 16) & 0x8000u); }
            else h[j] = 0u;
        }
        uint4 o;
        o.x = h[0] | (h[1] << 16);
        o.y = h[2] | (h[3] << 16);
        o.z = h[4] | (h[5] << 16);
        o.w = h[6] | (h[7] << 16);
        const int oc = (i & ~7) | ((i & 7) ^ sr);   // bank-true chunk swizzle
        out16[oc] = o;
    }
    #pragma unroll
    for (int off = 32; off; off >>= 1) { ks += __shfl_down(ks, off); kn += __shfl_down(kn, off); }
    if (lane == 0) { redA[wid] = ks; redB[wid] = kn; }
    __syncthreads();
    if (tid == 0) {
        float tks = redA[0] + redA[1] + redA[2] + redA[3];
        float tkn = redB[0] + redB[1] + redB[2] + redB[3];
        scale[row] = tks / fmaxf(tkn, 1.f);
    }
}

// ---------------- Kernel 2: cast x (f32) -> bf16, chunk-swizzled -----------
__global__ void __launch_bounds__(256) cast_x(
        const float* __restrict__ X, unsigned short* __restrict__ Xb,
        int n16, int cpr)   // n16 = total 16B chunks, cpr = chunks per row (IN/8)
{
    int idx = blockIdx.x * blockDim.x + threadIdx.x;
    int stride = gridDim.x * blockDim.x;
    const float4* x4 = (const float4*)X;
    uint4* o16 = (uint4*)Xb;
    for (int i = idx; i < n16; i += stride) {
        int m = i / cpr;                    // source row
        float4 a = x4[2 * i], b = x4[2 * i + 1];
        uint4 o;
        o.x = bfbits(a.x) | (bfbits(a.y) << 16);
        o.y = bfbits(a.z) | (bfbits(a.w) << 16);
        o.z = bfbits(b.x) | (bfbits(b.y) << 16);
        o.w = bfbits(b.z) | (bfbits(b.w) << 16);
        const int oc = (i & ~7) | ((i & 7) ^ swz_row(m));   // bank-true swizzle
        o16[oc] = o;
    }
}

// ---------------- Kernel 3: bf16 MFMA GEMM, C = Xb @ Wq^T * scale + bias ----
// BM=BN=128, BK=128. 512 threads = 8 waves: 2x2 spatial grid of 64x64 wave
// tiles x 2 K-groups (kg owns k[kg*64, kg*64+64) of each step). 32x32x16
// MFMA, 2x2 frags per wave. Double-buffered LDS (128 KB), depth-2
// counted-vmcnt pipeline. Producers chunk-swizzle with s(r) -> bank-true
// conflict-free reads. Final K-group merge through LDS (aliased).
#define BM 128
#define BN 128
#define BK 128
#define THREADS 512

__global__ void __launch_bounds__(512, 2) gemm_tern(
        const unsigned short* __restrict__ Xb,   // [M][K] bf16 bits, swizzled
        const unsigned short* __restrict__ Wq,   // [N][K] bf16 bits, swizzled
        const float* __restrict__ scale,         // [N]
        const float* __restrict__ bias,          // [N]
        float* __restrict__ C,                   // [M][N] f32
        int M, int N, int K)
{
    __shared__ __attribute__((aligned(16))) union SMem {
        struct { unsigned short A[2][BM * BK]; unsigned short B[2][BN * BK]; } s; // 128 KB
        float merge[4][64 * 64];                                                  // 64 KB
    } u;

    const int tid  = threadIdx.x;
    const int lane = tid & 63;
    const int wid  = tid >> 6;   // 0..7
    const int kg   = wid >> 2;   // K-group 0/1
    const int wq   = wid & 3;    // spatial wave id
    const int wr   = wq >> 1;    // 0..1 (M)
    const int wc   = wq & 1;     // 0..1 (N)

    // XCD-aware bijective swizzle (nwg=256, divisible by 8)
    const int nwg = gridDim.x;
    const int bid = blockIdx.x;
    const int swz = (bid & 7) * (nwg >> 3) + (bid >> 3);
    const int ntn = N / BN;                   // 8
    const int bm0 = (swz / ntn) * BM;
    const int bn0 = (swz % ntn) * BN;

    f32x16 acc[2][2];
    #pragma unroll
    for (int m = 0; m < 2; ++m)
        #pragma unroll
        for (int n = 0; n < 2; ++n)
            #pragma unroll
            for (int r = 0; r < 16; ++r)
                acc[m][n][r] = 0.f;

    const unsigned short* Ag = Xb + (size_t)bm0 * K;
    const unsigned short* Bg = Wq + (size_t)bn0 * K;

    // staging: tile = 128 rows x 16 chunks of 16B = 2048 slots; 4 calls/thread
    int srow[4], schk[4];
    #pragma unroll
    for (int c = 0; c < 4; ++c) {
        int slot = c * THREADS + tid;
        srow[c] = slot >> 4;
        schk[c] = slot & 15;
    }
    const int ldsbase = (tid & ~63) * 8;   // wave-uniform element base (+c*4096)

    #define STAGE(buf, t)                                                          \
        do {                                                                       \
            _Pragma("unroll")                                                      \
            for (int c = 0; c < 4; ++c) {                                          \
                __builtin_amdgcn_global_load_lds(                                  \
                    (const __attribute__((address_space(1))) unsigned int*)        \
                        (Ag + (size_t)srow[c] * K + (size_t)((t) * 16 + schk[c]) * 8), \
                    (__attribute__((address_space(3))) unsigned int*)              \
                        (&u.s.A[buf][c * 4096 + ldsbase]),                         \
                    16, 0, 0);                                                     \
                __builtin_amdgcn_global_load_lds(                                  \
                    (const __attribute__((address_space(1))) unsigned int*)        \
                        (Bg + (size_t)srow[c] * K + (size_t)((t) * 16 + schk[c]) * 8), \
                    (__attribute__((address_space(3))) unsigned int*)              \
                        (&u.s.B[buf][c * 4096 + ldsbase]),                         \
                    16, 0, 0);                                                     \
            }                                                                      \
        } while (0)

    const int NT = K / BK;             // 32
    const int r_a = wr * 64 + (lane & 31);   // A row base (m adds 32)
    const int r_b = wc * 64 + (lane & 31);   // B row base (n adds 32)
    const int khalf = lane >> 5;             // 0/1 (k-chunk half within 16-K)

    STAGE(0, 0);
    int cur = 0;

    for (int t = 0; t < NT; ++t) {
        if (t + 1 < NT) {
            STAGE(cur ^ 1, t + 1);
            asm volatile("s_waitcnt vmcnt(8)" ::: "memory");  // my tile-t loads done
        } else {
            asm volatile("s_waitcnt vmcnt(0)" ::: "memory");
        }
        __builtin_amdgcn_s_barrier();                         // tile t staged (all)

        short8 af[4][2], bf[4][2];
        #pragma unroll
        for (int kk = 0; kk < 4; ++kk) {
            #pragma unroll
            for (int m = 0; m < 2; ++m) {
                int r = r_a + m * 32;
                int chk = kg * 8 + ((kk * 2 + khalf) ^ swz_row(r));
                af[kk][m] = *(const short8*)&u.s.A[cur][r * BK + chk * 8];
            }
            #pragma unroll
            for (int n = 0; n < 2; ++n) {
                int r = r_b + n * 32;
                int chk = kg * 8 + ((kk * 2 + khalf) ^ swz_row(r));
                bf[kk][n] = *(const short8*)&u.s.B[cur][r * BK + chk * 8];
            }
        }
        __builtin_amdgcn_s_setprio(1);
        #pragma unroll
        for (int kk = 0; kk < 4; ++kk)
            #pragma unroll
            for (int m = 0; m < 2; ++m)
                #pragma unroll
                for (int n = 0; n < 2; ++n)
                    acc[m][n] = __builtin_amdgcn_mfma_f32_32x32x16_bf16(
                        af[kk][m], bf[kk][n], acc[m][n], 0, 0, 0);
        __builtin_amdgcn_s_setprio(0);
        __builtin_amdgcn_s_barrier();    // all reads of buf `cur` done before restage
        cur ^= 1;
    }

    // ---- K-group merge through LDS (aliases staging buffers; loop is done) ----
    if (kg == 1) {
        #pragma unroll
        for (int m = 0; m < 2; ++m)
            #pragma unroll
            for (int n = 0; n < 2; ++n)
                #pragma unroll
                for (int r = 0; r < 16; ++r)
                    u.merge[wq][((m * 2 + n) * 16 + r) * 64 + lane] = acc[m][n][r];
    }
    __syncthreads();
    if (kg == 0) {
        #pragma unroll
        for (int n = 0; n < 2; ++n) {
            int col = bn0 + wc * 64 + n * 32 + (lane & 31);
            float sc = scale[col];
            float bs = bias[col];
            #pragma unroll
            for (int m = 0; m < 2; ++m) {
                #pragma unroll
                for (int r = 0; r < 16; ++r) {
                    float v = acc[m][n][r] + u.merge[wq][((m * 2 + n) * 16 + r) * 64 + lane];
                    int row = bm0 + wr * 64 + m * 32 + (r & 3) + 8 * (r >> 2) + 4 * (lane >> 5);
                    C[(size_t)row * N + col] = v * sc + bs;
                }
            }
        }
    }
    #undef STAGE
}

extern "C" void kernel_launch(void* const* d_in, const int* in_sizes, int n_in,
                              void* d_out, int out_size, void* d_ws, size_t ws_size,
                              hipStream_t stream)
{
    const float* x    = (const float*)d_in[0];
    const float* w    = (const float*)d_in[1];
    const float* bias = (const float*)d_in[2];
    float* out = (float*)d_out;

    const int OUT = in_sizes[2];            // 1024
    const int IN  = in_sizes[1] / OUT;      // 4096
    const int B   = in_sizes[0] / IN;       // 4096

    // workspace layout: x_bf16 [B*IN] | w_tern_bf16 [OUT*IN] | scale [OUT]
    unsigned short* Xb = (unsigned short*)d_ws;
    unsigned short* Wq = Xb + (size_t)B * IN;
    float* scale = (float*)(Wq + (size_t)OUT * IN);

    quant_tern<<<OUT, 256, 0, stream>>>(w, Wq, scale, IN);
    cast_x<<<2048, 256, 0, stream>>>(x, Xb, (B * IN) / 8, IN / 8);
    gemm_tern<<<dim3((B / BM) * (OUT / BN)), THREADS, 0, stream>>>(
        Xb, Wq, scale, bias, out, B, OUT, IN);
}